// Round 9
// baseline (391.458 us; speedup 1.0000x reference)
//
#include <hip/hip_runtime.h>
#include <math.h>

#define NN 100000
#define NE 800000
#define C1 256      // HEADS*HID
#define OC 40
#define XPAD 64     // xp2 row stride (fp16) = 128 B = 1 cacheline
#define PADMAX 1600000   // worst-case padded slots: sum(deg+7) = 900k + 700k
#define NEG 0.2f

typedef _Float16 h4 __attribute__((ext_vector_type(4)));
typedef _Float16 h8 __attribute__((ext_vector_type(8)));
typedef float f4v __attribute__((ext_vector_type(4)));
typedef float f2v __attribute__((ext_vector_type(2)));

static __device__ __forceinline__ float leaky(float v){ return v > 0.f ? v : NEG*v; }

static __device__ __forceinline__ h8 cvt8(const float4* p){
  float4 a = p[0], b = p[1];
  h8 r = {(_Float16)a.x,(_Float16)a.y,(_Float16)a.z,(_Float16)a.w,
          (_Float16)b.x,(_Float16)b.y,(_Float16)b.z,(_Float16)b.w};
  return r;
}

// Permuted xp1/h1 row layout: storage element e = 4*l + j (l = dword 0..63, j = byte 0..3)
// holds logical col pcol(l,j) = (l>>5)*128 + ((l>>4)&1)*64 + 16*j + (l&15).
// Head of (l,j): bytes 0,1 -> hA = 2*(l>>4); bytes 2,3 -> hA+1.

// ---------------- W1t (fp16 col-major) + W2t (fp16, k-permuted) ----------------
__global__ __launch_bounds__(256) void k_wt(const float* __restrict__ W1, const float* __restrict__ W2,
                                            _Float16* __restrict__ W1t, _Float16* __restrict__ W2t){
  int b = blockIdx.x;
  if (b < 128){
    int k = b, nb = threadIdx.x;
    W1t[(size_t)nb*128 + k] = (_Float16)W1[k*256 + nb];
  } else {
    int nb = b - 128;            // 0..47 (pad 40->48 with zeros)
    int e = threadIdx.x;         // storage index 0..255
    int l = e >> 2, j = e & 3;
    int k = (l>>5)*128 + ((l>>4)&1)*64 + j*16 + (l&15);
    float v = (nb < OC) ? W2[(size_t)k*OC + nb] : 0.f;
    W2t[(size_t)nb*256 + e] = (_Float16)v;
  }
}

// ---------------- K1: xp1 = x @ W1 via fp16 MFMA -> packed fp8 dword stores + attention dots ----------------
__global__ __launch_bounds__(256) void k_gemm1(const float* __restrict__ x,
    const _Float16* __restrict__ W1t, const float* __restrict__ attS,
    const float* __restrict__ attD, unsigned* __restrict__ xp1w,
    float* __restrict__ asrc, float* __restrict__ adst)
{
  const int tid  = threadIdx.x;
  const int lane = tid & 63;
  const int w    = tid >> 6;
  const int wr = w >> 1, wc = w & 1;
  const int n = lane & 15, quad = lane >> 4;
  const int r0 = blockIdx.x * 64;

  float aSc[8], aDc[8];
  #pragma unroll
  for (int ct = 0; ct < 8; ++ct){
    int col = wc*128 + ct*16 + n;
    aSc[ct] = attS[col]; aDc[ct] = attD[col];
  }

  f4v acc[2][8];
  #pragma unroll
  for (int rt = 0; rt < 2; ++rt)
    #pragma unroll
    for (int ct = 0; ct < 8; ++ct) acc[rt][ct] = (f4v){0.f,0.f,0.f,0.f};

  const int row0 = r0 + wr*32 + n;
  const int ra = (row0      < NN) ? row0      : NN-1;
  const int rb = (row0 + 16 < NN) ? row0 + 16 : NN-1;

  #pragma unroll
  for (int ks = 0; ks < 4; ++ks){
    h8 a0 = cvt8((const float4*)(x + (size_t)ra*128 + ks*32 + quad*8));
    h8 a1 = cvt8((const float4*)(x + (size_t)rb*128 + ks*32 + quad*8));
    #pragma unroll
    for (int ct = 0; ct < 8; ++ct){
      h8 b = *(const h8*)(W1t + (size_t)(wc*128 + ct*16 + n)*128 + ks*32 + quad*8);
      acc[0][ct] = __builtin_amdgcn_mfma_f32_16x16x32_f16(a0, b, acc[0][ct], 0, 0, 0);
      acc[1][ct] = __builtin_amdgcn_mfma_f32_16x16x32_f16(a1, b, acc[1][ct], 0, 0, 0);
    }
  }

  #pragma unroll
  for (int rt = 0; rt < 2; ++rt){
    #pragma unroll
    for (int reg = 0; reg < 4; ++reg){
      const int row = r0 + wr*32 + rt*16 + quad*4 + reg;
      const bool ok = row < NN;
      float v[8];
      #pragma unroll
      for (int ct = 0; ct < 8; ++ct) v[ct] = acc[rt][ct][reg];
      if (ok){
        unsigned dwA = (unsigned)__builtin_amdgcn_cvt_pk_fp8_f32(v[0], v[1], 0, false);
        dwA = (unsigned)__builtin_amdgcn_cvt_pk_fp8_f32(v[2], v[3], (int)dwA, true);
        unsigned dwB = (unsigned)__builtin_amdgcn_cvt_pk_fp8_f32(v[4], v[5], 0, false);
        dwB = (unsigned)__builtin_amdgcn_cvt_pk_fp8_f32(v[6], v[7], (int)dwB, true);
        unsigned* xr = xp1w + (size_t)row*64 + wc*32 + n;
        xr[0]  = dwA;
        xr[16] = dwB;
      }
      float s[4], d[4];
      #pragma unroll
      for (int h = 0; h < 4; ++h){
        s[h] = v[2*h]*aSc[2*h] + v[2*h+1]*aSc[2*h+1];
        d[h] = v[2*h]*aDc[2*h] + v[2*h+1]*aDc[2*h+1];
      }
      #pragma unroll
      for (int off = 1; off < 16; off <<= 1){
        #pragma unroll
        for (int h = 0; h < 4; ++h){
          s[h] += __shfl_xor(s[h], off, 64);
          d[h] += __shfl_xor(d[h], off, 64);
        }
      }
      if (ok && n == 0){
        #pragma unroll
        for (int h = 0; h < 4; ++h){
          asrc[row*8 + wc*4 + h] = s[h];
          adst[row*8 + wc*4 + h] = d[h];
        }
      }
    }
  }
}

// ---------------- CSR build, 8-aligned padded rows; self-loop via deg init = 1 ----------------
__global__ __launch_bounds__(256) void k_deg_init(int* deg){
  int i = blockIdx.x*256 + threadIdx.x;
  if (i < NN) deg[i] = 1;
}
__global__ __launch_bounds__(256) void k_deg_count(const int* __restrict__ ei, int* deg){
  int i = blockIdx.x*256 + threadIdx.x;
  if (i < NE) atomicAdd(&deg[ei[NE + i]], 1);
}
// scan over PADDED degrees: pd = ceil(deg/8)*8
__global__ __launch_bounds__(256) void k_scan1(const int* __restrict__ deg, int* part, int* bsum){
  __shared__ int lds[256];
  const int t = threadIdx.x;
  const int base = blockIdx.x*1024;
  int v[4]; int s = 0;
  #pragma unroll
  for (int i = 0; i < 4; ++i){
    int idx = base + t*4 + i;
    v[i] = (idx < NN) ? ((deg[idx] + 7) & ~7) : 0;
    s += v[i];
  }
  lds[t] = s; __syncthreads();
  for (int off = 1; off < 256; off <<= 1){
    int xx = (t >= off) ? lds[t-off] : 0;
    __syncthreads();
    lds[t] += xx;
    __syncthreads();
  }
  int excl = lds[t] - s;
  #pragma unroll
  for (int i = 0; i < 4; ++i){ int idx = base + t*4 + i; if (idx < NN) part[idx] = excl; excl += v[i]; }
  if (t == 255) bsum[blockIdx.x] = lds[255];
}
__global__ void k_scan2(const int* __restrict__ bsum, int* boff, int* rowptrN){
  const int l = threadIdx.x;
  int a = (l      < 98) ? bsum[l]      : 0;
  int b = (64 + l < 98) ? bsum[64 + l] : 0;
  int sa = a, sb = b;
  #pragma unroll
  for (int off = 1; off < 64; off <<= 1){
    int ta = __shfl_up(sa, off, 64);
    int tb = __shfl_up(sb, off, 64);
    if (l >= off){ sa += ta; sb += tb; }
  }
  const int totalA = __shfl(sa, 63, 64);
  if (l      < 98) boff[l]      = sa - a;
  if (64 + l < 98) boff[64 + l] = totalA + sb - b;
  if (64 + l == 97) rowptrN[0] = totalA + sb;   // total padded slot count
}
__global__ __launch_bounds__(256) void k_scan3(const int* __restrict__ part, const int* __restrict__ boff,
                                               int* rowptr, int* cursor){
  int i = blockIdx.x*256 + threadIdx.x;
  if (i < NN){ int v = part[i] + boff[i >> 10]; rowptr[i] = v; cursor[i] = v; }
}
__global__ __launch_bounds__(256) void k_padinit(int* esrc, int* edst){
  int i = blockIdx.x*256 + threadIdx.x;
  if (i < PADMAX){ esrc[i] = 0; edst[i] = -1; }
}
__global__ __launch_bounds__(256) void k_fill(const int* __restrict__ ei, int* cursor,
                                              int* __restrict__ esrc, int* __restrict__ edst){
  int i = blockIdx.x*256 + threadIdx.x;
  if (i < NE + NN){
    int s, d;
    if (i < NE){ s = ei[i]; d = ei[NE + i]; } else { s = d = i - NE; }
    int slot = atomicAdd(&cursor[d], 1);
    esrc[slot] = s;
    edst[slot] = d;
  }
}

// ---------------- edge-parallel p precompute, layer 1: pt[h][slot] ----------------
__global__ __launch_bounds__(256) void k_pedge1(const int* __restrict__ esrc, const int* __restrict__ edst,
    const float* __restrict__ asrc, const float* __restrict__ adst, float* __restrict__ pt){
  int i = blockIdx.x*256 + threadIdx.x;
  if (i >= PADMAX) return;
  int d = edst[i];
  if (d < 0){
    #pragma unroll
    for (int h = 0; h < 8; ++h) pt[(size_t)h*PADMAX + i] = 0.f;
    return;
  }
  int s = esrc[i];
  float4 a0 = ((const float4*)(asrc + (size_t)s*8))[0];
  float4 a1 = ((const float4*)(asrc + (size_t)s*8))[1];
  float4 d0 = ((const float4*)(adst + (size_t)d*8))[0];
  float4 d1 = ((const float4*)(adst + (size_t)d*8))[1];
  float v[8] = {a0.x+d0.x, a0.y+d0.y, a0.z+d0.z, a0.w+d0.w,
                a1.x+d1.x, a1.y+d1.y, a1.z+d1.z, a1.w+d1.w};
  #pragma unroll
  for (int h = 0; h < 8; ++h) pt[(size_t)h*PADMAX + i] = __expf(leaky(v[h]));
}

// ---------------- edge-parallel p precompute, layer 2: p2t[slot] ----------------
__global__ __launch_bounds__(256) void k_pedge2(const int* __restrict__ esrc, const int* __restrict__ edst,
    const float* __restrict__ asrc2, const float* __restrict__ adst2, float* __restrict__ p2t){
  int i = blockIdx.x*256 + threadIdx.x;
  if (i >= PADMAX) return;
  int d = edst[i];
  float p = 0.f;
  if (d >= 0) p = __expf(leaky(asrc2[esrc[i]] + adst2[d]));
  p2t[i] = p;
}

// ---------------- K3: layer-1 aggregation. Full 8-slot batches, p from registers ----------------
__global__ __launch_bounds__(256) void k_agg1(const unsigned* __restrict__ xp1w,
    const float* __restrict__ pt, const float* __restrict__ b1,
    const int* __restrict__ rowptrp, const int* __restrict__ esrc, _Float16* __restrict__ h1)
{
  const int lane = threadIdx.x & 63;
  int n = __builtin_amdgcn_readfirstlane(blockIdx.x*4 + (threadIdx.x >> 6));
  const int hA = (lane >> 4) * 2;     // bytes 0,1 -> head hA; bytes 2,3 -> hA+1
  const int jb = rowptrp[n], je = rowptrp[n+1];   // multiples of 8
  const int cbase = (lane>>5)*128 + ((lane>>4)&1)*64 + (lane&15);
  const float bp0 = b1[cbase], bp1 = b1[cbase+16], bp2 = b1[cbase+32], bp3 = b1[cbase+48];
  float4 acc = make_float4(0,0,0,0);
  float zA = 0.f, zB = 0.f;

  for (int j0 = jb; j0 < je; j0 += 8) {
    // p for my two heads: 4 aligned float4 loads (j0 is 8-aligned -> 32B aligned)
    const float4* pa4 = (const float4*)(pt + (size_t)hA*PADMAX + j0);
    const float4* pb4 = (const float4*)(pt + (size_t)(hA+1)*PADMAX + j0);
    float4 pa0 = pa4[0], pa1 = pa4[1];
    float4 pb0 = pb4[0], pb1 = pb4[1];
    const int sv = esrc[j0 + (lane & 7)];
    // phase 1: 8 unconditional row loads (pads point at row 0 -> L1 hits)
    unsigned u[8];
    #pragma unroll
    for (int e = 0; e < 8; ++e){
      int s = __builtin_amdgcn_readfirstlane(__shfl(sv, e, 64));
      u[e] = xp1w[(size_t)s*64 + lane];
    }
    __builtin_amdgcn_sched_barrier(0);   // loads issued before FMAs
    zA += (pa0.x+pa0.y+pa0.z+pa0.w) + (pa1.x+pa1.y+pa1.z+pa1.w);
    zB += (pb0.x+pb0.y+pb0.z+pb0.w) + (pb1.x+pb1.y+pb1.z+pb1.w);
    const float pA[8] = {pa0.x,pa0.y,pa0.z,pa0.w,pa1.x,pa1.y,pa1.z,pa1.w};
    const float pB[8] = {pb0.x,pb0.y,pb0.z,pb0.w,pb1.x,pb1.y,pb1.z,pb1.w};
    #pragma unroll
    for (int e = 0; e < 8; ++e){
      f2v lo = __builtin_amdgcn_cvt_pk_f32_fp8((int)u[e], false);
      f2v hi = __builtin_amdgcn_cvt_pk_f32_fp8((int)u[e], true);
      acc.x += pA[e]*lo.x; acc.y += pA[e]*lo.y;
      acc.z += pB[e]*hi.x; acc.w += pB[e]*hi.y;
    }
  }
  const float invA = 1.f/(zA + 1e-16f), invB = 1.f/(zB + 1e-16f);
  h4 o = {(_Float16)fmaxf(acc.x*invA + bp0, 0.f),
          (_Float16)fmaxf(acc.y*invA + bp1, 0.f),
          (_Float16)fmaxf(acc.z*invB + bp2, 0.f),
          (_Float16)fmaxf(acc.w*invB + bp3, 0.f)};
  ((h4*)h1)[(size_t)n*64 + lane] = o;
}

// ---------------- K4: xp2 = h1 @ W2 via fp16 MFMA (k permuted on both A and B) ----------------
__global__ __launch_bounds__(256) void k_gemm2(const _Float16* __restrict__ h1,
    const _Float16* __restrict__ W2t, const float* __restrict__ attS,
    const float* __restrict__ attD, _Float16* __restrict__ xp2,
    float* __restrict__ asrc2, float* __restrict__ adst2)
{
  const int tid  = threadIdx.x;
  const int lane = tid & 63;
  const int w    = tid >> 6;
  const int n = lane & 15, quad = lane >> 4;
  const int r0 = blockIdx.x * 256 + w*64;

  float aSc[3], aDc[3];
  #pragma unroll
  for (int ct = 0; ct < 3; ++ct){
    int col = ct*16 + n;
    aSc[ct] = (col < OC) ? attS[col] : 0.f;
    aDc[ct] = (col < OC) ? attD[col] : 0.f;
  }

  f4v acc[4][3];
  #pragma unroll
  for (int rt = 0; rt < 4; ++rt)
    #pragma unroll
    for (int ct = 0; ct < 3; ++ct) acc[rt][ct] = (f4v){0.f,0.f,0.f,0.f};

  int rr[4];
  #pragma unroll
  for (int rt = 0; rt < 4; ++rt){
    int r = r0 + rt*16 + n;
    rr[rt] = (r < NN) ? r : NN-1;
  }

  #pragma unroll
  for (int ks = 0; ks < 8; ++ks){
    h8 b[3];
    #pragma unroll
    for (int ct = 0; ct < 3; ++ct)
      b[ct] = *(const h8*)(W2t + (size_t)(ct*16 + n)*256 + ks*32 + quad*8);
    #pragma unroll
    for (int rt = 0; rt < 4; ++rt){
      h8 a = *(const h8*)(h1 + (size_t)rr[rt]*256 + ks*32 + quad*8);
      #pragma unroll
      for (int ct = 0; ct < 3; ++ct)
        acc[rt][ct] = __builtin_amdgcn_mfma_f32_16x16x32_f16(a, b[ct], acc[rt][ct], 0, 0, 0);
    }
  }

  #pragma unroll
  for (int rt = 0; rt < 4; ++rt){
    #pragma unroll
    for (int reg = 0; reg < 4; ++reg){
      const int row = r0 + rt*16 + quad*4 + reg;
      const bool ok = row < NN;
      float v0 = acc[rt][0][reg], v1 = acc[rt][1][reg], v2 = acc[rt][2][reg];
      float s = v0*aSc[0] + v1*aSc[1] + v2*aSc[2];
      float d = v0*aDc[0] + v1*aDc[1] + v2*aDc[2];
      #pragma unroll
      for (int off = 1; off < 16; off <<= 1){
        s += __shfl_xor(s, off, 64);
        d += __shfl_xor(d, off, 64);
      }
      if (ok){
        _Float16* xr = xp2 + (size_t)row*XPAD + n;
        xr[0]  = (_Float16)v0;
        xr[16] = (_Float16)v1;
        if (n < 8) xr[32] = (_Float16)v2;
        if (n == 0){ asrc2[row] = s; adst2[row] = d; }
      }
    }
  }
}

// ---------------- K5: layer-2 aggregation. Full 8-slot batches, uniform p ----------------
__global__ __launch_bounds__(256) void k_agg2(const _Float16* __restrict__ xp2,
    const float* __restrict__ p2t, const float* __restrict__ b2,
    const int* __restrict__ rowptrp, const int* __restrict__ esrc, float* __restrict__ out)
{
  const int lane = threadIdx.x & 63;
  int n = __builtin_amdgcn_readfirstlane(blockIdx.x*4 + (threadIdx.x >> 6));
  const int jb = rowptrp[n], je = rowptrp[n+1];
  const bool act = lane < OC;
  float acc = 0.f, z = 0.f;

  for (int j0 = jb; j0 < je; j0 += 8) {
    const float4* pp = (const float4*)(p2t + j0);   // uniform address -> broadcast
    float4 p0 = pp[0], p1 = pp[1];
    const int sv = esrc[j0 + (lane & 7)];
    _Float16 u[8];
    #pragma unroll
    for (int e = 0; e < 8; ++e){
      int s = __builtin_amdgcn_readfirstlane(__shfl(sv, e, 64));
      u[e] = xp2[(size_t)s*XPAD + lane];
    }
    __builtin_amdgcn_sched_barrier(0);
    z += (p0.x+p0.y+p0.z+p0.w) + (p1.x+p1.y+p1.z+p1.w);
    const float pv[8] = {p0.x,p0.y,p0.z,p0.w,p1.x,p1.y,p1.z,p1.w};
    #pragma unroll
    for (int e = 0; e < 8; ++e) acc += pv[e] * (float)u[e];
  }

  float val = act ? (acc/(z + 1e-16f) + b2[lane]) : -INFINITY;
  float m = val;
  #pragma unroll
  for (int off = 32; off > 0; off >>= 1) m = fmaxf(m, __shfl_xor(m, off, 64));
  float e = act ? __expf(val - m) : 0.f;
  float sum = e;
  #pragma unroll
  for (int off = 32; off > 0; off >>= 1) sum += __shfl_xor(sum, off, 64);
  if (act) out[(size_t)n*OC + lane] = val - m - __logf(sum);
}

extern "C" void kernel_launch(void* const* d_in, const int* in_sizes, int n_in,
                              void* d_out, int out_size, void* d_ws, size_t ws_size,
                              hipStream_t stream)
{
  const float* x   = (const float*)d_in[0];
  const int*   ei  = (const int*)  d_in[1];
  const float* W1  = (const float*)d_in[2];
  const float* aS1 = (const float*)d_in[3];
  const float* aD1 = (const float*)d_in[4];
  const float* b1  = (const float*)d_in[5];
  const float* W2  = (const float*)d_in[6];
  const float* aS2 = (const float*)d_in[7];
  const float* aD2 = (const float*)d_in[8];
  const float* b2  = (const float*)d_in[9];
  float* out = (float*)d_out;

  char* wsp = (char*)d_ws;
  size_t off = 0;
  auto alloc = [&](size_t bytes){ void* p = wsp + off; off += (bytes + 255) & ~(size_t)255; return p; };
  unsigned* xp1w = (unsigned*)alloc((size_t)NN*C1);            // fp8, permuted, 64 dwords/row (25.6MB)
  _Float16* h1  = (_Float16*)alloc((size_t)NN*C1*2);           // fp16, permuted cols (51.2MB)
  float* as1  = (float*)alloc((size_t)NN*8*4);
  float* ad1  = (float*)alloc((size_t)NN*8*4);
  float* as2  = (float*)alloc((size_t)NN*4);
  float* ad2  = (float*)alloc((size_t)NN*4);
  int* deg    = (int*)alloc((size_t)NN*4);
  int* part   = (int*)alloc((size_t)NN*4);
  int* rowptr = (int*)alloc((size_t)(NN+1)*4);
  int* cursor = (int*)alloc((size_t)NN*4);
  int* bsum   = (int*)alloc(98*4);
  int* boff   = (int*)alloc(98*4);
  int* esrc   = (int*)alloc((size_t)PADMAX*4);
  int* edst   = (int*)alloc((size_t)PADMAX*4);
  float* pt   = (float*)alloc((size_t)8*PADMAX*4);             // 51.2MB
  float* p2t  = (float*)alloc((size_t)PADMAX*4);
  _Float16* W1t = (_Float16*)alloc((size_t)256*128*2);
  _Float16* W2t = (_Float16*)alloc((size_t)48*256*2);
  _Float16* xp2 = (_Float16*)alloc((size_t)NN*XPAD*2);         // 12.8MB
  (void)ws_size; (void)in_sizes; (void)n_in; (void)out_size;

  k_wt       <<<176,  256, 0, stream>>>(W1, W2, W1t, W2t);
  k_gemm1    <<<1563, 256, 0, stream>>>(x, W1t, aS1, aD1, xp1w, as1, ad1);
  k_deg_init <<<391,  256, 0, stream>>>(deg);
  k_deg_count<<<3125, 256, 0, stream>>>(ei, deg);
  k_scan1    <<<98,   256, 0, stream>>>(deg, part, bsum);
  k_scan2    <<<1,    64,  0, stream>>>(bsum, boff, rowptr + NN);
  k_scan3    <<<391,  256, 0, stream>>>(part, boff, rowptr, cursor);
  k_padinit  <<<6250, 256, 0, stream>>>(esrc, edst);
  k_fill     <<<3516, 256, 0, stream>>>(ei, cursor, esrc, edst);
  k_pedge1   <<<6250, 256, 0, stream>>>(esrc, edst, as1, ad1, pt);
  k_agg1     <<<25000,256, 0, stream>>>(xp1w, pt, b1, rowptr, esrc, h1);
  k_gemm2    <<<391,  256, 0, stream>>>(h1, W2t, aS2, aD2, xp2, as2, ad2);
  k_pedge2   <<<6250, 256, 0, stream>>>(esrc, edst, as2, ad2, p2t);
  k_agg2     <<<25000,256, 0, stream>>>(xp2, p2t, b2, rowptr, esrc, out);
}